// Round 9
// baseline (385.128 us; speedup 1.0000x reference)
//
#include <hip/hip_runtime.h>
#include <cstdint>
#include <cstddef>

typedef unsigned short u16;
typedef unsigned int   u32;

#define E_DIM 768
#define NH    12
#define HD    64
#define SEQ   2048
#define NBATCH 4
#define NBH   48          // NBATCH*NH
#define MTOT  8192        // NBATCH*SEQ
#define NQKV  2304
// 0.125 * log2(e): QK^T scores land in log2 domain -> softmax uses raw v_exp_f32
#define QSCALE 0.18033688011112042f

typedef __bf16 bf16x8 __attribute__((ext_vector_type(8)));
typedef float  f32x4  __attribute__((ext_vector_type(4)));

__device__ __forceinline__ u16 f2b(float f) {
  u32 u = __builtin_bit_cast(u32, f);
  u32 r = (u + 0x7fffu + ((u >> 16) & 1u)) >> 16;   // RNE, finite inputs only
  return (u16)r;
}
__device__ __forceinline__ u32 cvtpk(float a, float b) {   // dst = bf16(a) | bf16(b)<<16
  u32 r;
  asm("v_cvt_pk_bf16_f32 %0, %1, %2" : "=v"(r) : "v"(a), "v"(b));
  return r;
}
__device__ __forceinline__ float exp2fast(float x) {
  float r;
  asm("v_exp_f32 %0, %1" : "=v"(r) : "v"(x));
  return r;
}
__device__ __forceinline__ f32x4 mfma16(bf16x8 a, bf16x8 b, f32x4 c) {
  return __builtin_amdgcn_mfma_f32_16x16x32_bf16(a, b, c, 0, 0, 0);
}
__device__ __forceinline__ void gload_lds16(const void* g, void* l) {
  __builtin_amdgcn_global_load_lds((const __attribute__((address_space(1))) void*)g,
                                   (__attribute__((address_space(3))) void*)l, 16, 0, 0);
}

// ---------------- x fp32 -> bf16 ----------------
__global__ void k_cvt_x(const float4* __restrict__ x, uint2* __restrict__ xb) {
  int i = blockIdx.x * 256 + threadIdx.x;     // grid sized exactly: 6291456/4 elems
  float4 v = x[i];
  uint2 o;
  o.x = cvtpk(v.x, v.y);
  o.y = cvtpk(v.z, v.w);
  xb[i] = o;
}

// ------------- W [K][N] fp32 -> Wt [N][K] bf16 -------------
__global__ __launch_bounds__(256) void k_wtrans(const float* __restrict__ w, u16* __restrict__ wt,
                                                int K, int N) {
  __shared__ float t[64][65];
  int n0 = blockIdx.x * 64, k0 = blockIdx.y * 64;
  int tid = threadIdx.x;
#pragma unroll
  for (int it = 0; it < 16; ++it) {
    int idx = it * 256 + tid;
    int r = idx >> 6, c = idx & 63;          // r = k-local, c = n-local
    t[r][c] = w[(size_t)(k0 + r) * N + n0 + c];
  }
  __syncthreads();
#pragma unroll
  for (int it = 0; it < 16; ++it) {
    int idx = it * 256 + tid;
    int r = idx >> 6, c = idx & 63;          // r = n-local, c = k-local
    wt[(size_t)(n0 + r) * K + k0 + c] = f2b(t[c][r]);
  }
}

// ------------- GEMM mainloop (m97-style): A[M][768] bf16 x Bt[N][768] bf16 -------------
#define GEMM_MAIN(A_, Bt_)                                                              \
  __shared__ u16 As[128 * 32];                                                          \
  __shared__ u16 Bs[128 * 32];                                                          \
  const int tid = threadIdx.x;                                                          \
  const int m0 = blockIdx.x * 128, n0 = blockIdx.y * 128;                               \
  const int wave = tid >> 6, lane = tid & 63, ln = lane & 15, lg = lane >> 4;           \
  const int wr = wave >> 1, wc = wave & 1;                                              \
  f32x4 acc[4][4] = {};                                                                 \
  const int f0 = tid, f1 = tid + 256;                                                   \
  const size_t ga0 = (size_t)(m0 + (f0 >> 2)) * 768 + (f0 & 3) * 8;                     \
  const size_t ga1 = (size_t)(m0 + (f1 >> 2)) * 768 + (f1 & 3) * 8;                     \
  const size_t gb0 = (size_t)(n0 + (f0 >> 2)) * 768 + (f0 & 3) * 8;                     \
  const size_t gb1 = (size_t)(n0 + (f1 >> 2)) * 768 + (f1 & 3) * 8;                     \
  for (int kt = 0; kt < 24; ++kt) {                                                     \
    __syncthreads();                                                                    \
    gload_lds16(A_ + ga0 + kt * 32, &As[f0 * 8]);                                       \
    gload_lds16(A_ + ga1 + kt * 32, &As[f1 * 8]);                                       \
    gload_lds16(Bt_ + gb0 + kt * 32, &Bs[f0 * 8]);                                      \
    gload_lds16(Bt_ + gb1 + kt * 32, &Bs[f1 * 8]);                                      \
    __syncthreads();                                                                    \
    bf16x8 a[4], b[4];                                                                  \
    _Pragma("unroll") for (int i = 0; i < 4; ++i)                                       \
        a[i] = *(const bf16x8*)&As[(wr * 64 + i * 16 + ln) * 32 + lg * 8];              \
    _Pragma("unroll") for (int j = 0; j < 4; ++j)                                       \
        b[j] = *(const bf16x8*)&Bs[(wc * 64 + j * 16 + ln) * 32 + lg * 8];              \
    _Pragma("unroll") for (int i = 0; i < 4; ++i)                                       \
        _Pragma("unroll") for (int j = 0; j < 4; ++j)                                   \
            acc[i][j] = mfma16(a[i], b[j], acc[i][j]);                                  \
  }

// qkv = x @ Wqkv + b; scatter into Q(*QSCALE)/K [bh][s][d] and V^T [bh][d][s], all bf16
__global__ __launch_bounds__(256) void k_gemm_qkv(const u16* __restrict__ A, const u16* __restrict__ Bt,
                                                  const float* __restrict__ bias,
                                                  u16* __restrict__ Qw, u16* __restrict__ Kw,
                                                  u16* __restrict__ Vt) {
  GEMM_MAIN(A, Bt)
#pragma unroll
  for (int j = 0; j < 4; ++j) {
    int n = n0 + wc * 64 + j * 16 + ln;      // uniform route per frag (16-block never straddles 64-aligned splits)
    float bn = bias[n];
    if (n >= 1536) {                         // V: write transposed [bh][d][s], 4 consecutive s packed
      int h = (n - 1536) >> 6, d = (n - 1536) & 63;
#pragma unroll
      for (int i = 0; i < 4; ++i) {
        int mb = m0 + wr * 64 + i * 16 + lg * 4;   // 4-aligned; never crosses batch (2048|4)
        int bb = mb >> 11, s = mb & 2047;
        uint2 w;
        w.x = cvtpk(acc[i][j][0] + bn, acc[i][j][1] + bn);
        w.y = cvtpk(acc[i][j][2] + bn, acc[i][j][3] + bn);
        *(uint2*)&Vt[((size_t)(bb * NH + h) * HD + d) * SEQ + s] = w;
      }
    } else {
      u16* dst; int nn; float scale;
      if (n < 768) { dst = Qw; nn = n;       scale = QSCALE; }
      else         { dst = Kw; nn = n - 768; scale = 1.0f;  }
      int h = nn >> 6, d = nn & 63;
#pragma unroll
      for (int i = 0; i < 4; ++i) {
        int mb = m0 + wr * 64 + i * 16 + lg * 4;
#pragma unroll
        for (int r = 0; r < 4; ++r) {
          int m = mb + r;
          int bb = m >> 11, s = m & 2047;
          float v = (acc[i][j][r] + bn) * scale;
          dst[((size_t)(bb * NH + h) * SEQ + s) * HD + d] = f2b(v);
        }
      }
    }
  }
}

// out = attn_bf @ Wo + bo  (fp32 out)
__global__ __launch_bounds__(256) void k_gemm_out(const u16* __restrict__ A, const u16* __restrict__ Bt,
                                                  const float* __restrict__ bias, float* __restrict__ C) {
  GEMM_MAIN(A, Bt)
#pragma unroll
  for (int j = 0; j < 4; ++j) {
    int n = n0 + wc * 64 + j * 16 + ln;
    float bn = bias[n];
#pragma unroll
    for (int i = 0; i < 4; ++i) {
      int mb = m0 + wr * 64 + i * 16 + lg * 4;
#pragma unroll
      for (int r = 0; r < 4; ++r) {
        C[(size_t)(mb + r) * 768 + n] = acc[i][j][r] + bn;
      }
    }
  }
}

// ------------- flash attention: Q[bh][s][d] (pre-scaled by QSCALE), K[bh][s][d], Vt[bh][d][s]
//               -> Ob[b*S][E] bf16. Scores in log2 domain; defer-max THR=8. -------------
__global__ __launch_bounds__(256) void k_attn(const u16* __restrict__ Qw, const u16* __restrict__ Kw,
                                              const u16* __restrict__ Vt, u16* __restrict__ Ob) {
  __shared__ __align__(16) u16 P[4][32 * 72];   // per-wave P buffer: no __syncthreads in this kernel
  // XCD-bijective swizzle: 768 blocks = 8 XCDs x 96; all 16 q-tiles of a head (and 6 heads)
  // land on one XCD -> K/V (3 MB) L2-resident per XCD.
  const int wg = (blockIdx.x & 7) * 96 + (blockIdx.x >> 3);
  const int bh = wg >> 4;
  const int q0 = (wg & 15) * 128;
  const int wave = threadIdx.x >> 6, lane = threadIdx.x & 63, ln = lane & 15, lg = lane >> 4;
  const u16* Qb = Qw + ((size_t)bh * SEQ + q0 + wave * 32) * HD;
  const u16* Kb = Kw + (size_t)bh * SEQ * HD;
  const u16* Vb = Vt + (size_t)bh * HD * SEQ;
  u16* Pw = P[wave];

  bf16x8 qf[2][2];
#pragma unroll
  for (int qi = 0; qi < 2; ++qi)
#pragma unroll
    for (int kk = 0; kk < 2; ++kk)
      qf[qi][kk] = *(const bf16x8*)&Qb[(qi * 16 + ln) * HD + kk * 32 + lg * 8];

  f32x4 o[2][4] = {};
  float m_r[2] = {-1e30f, -1e30f}, l_r[2] = {0.f, 0.f};

  for (int t0 = 0; t0 < SEQ; t0 += 64) {
    // V loads issued FIRST: consumed only in PV at the end; the memory-clobber fences
    // below pin them early in program order -> ~1500 cyc of QK^T+softmax hides them.
    bf16x8 bv[2][4];
#pragma unroll
    for (int tk = 0; tk < 2; ++tk)
#pragma unroll
      for (int df = 0; df < 4; ++df)
        bv[tk][df] = *(const bf16x8*)&Vb[(size_t)(df * 16 + ln) * SEQ + t0 + tk * 32 + lg * 8];

    // S^T = K * Q  (swapped: softmax stats land on lane&15)
    f32x4 st[4][2];
#pragma unroll
    for (int tf = 0; tf < 4; ++tf) {
      bf16x8 k0 = *(const bf16x8*)&Kb[(size_t)(t0 + tf * 16 + ln) * HD + lg * 8];
      bf16x8 k1 = *(const bf16x8*)&Kb[(size_t)(t0 + tf * 16 + ln) * HD + 32 + lg * 8];
#pragma unroll
      for (int qi = 0; qi < 2; ++qi) {
        f32x4 z = {0.f, 0.f, 0.f, 0.f};
        z = mfma16(k0, qf[qi][0], z);
        z = mfma16(k1, qf[qi][1], z);
        st[tf][qi] = z;
      }
    }
    // online softmax in log2 domain (per q-column = lane&15), defer-max (T13, THR=8)
    float mnew[2], corr[2];
    bool skip[2];
#pragma unroll
    for (int qi = 0; qi < 2; ++qi) {
      float mx = st[0][qi][0];
#pragma unroll
      for (int tf = 0; tf < 4; ++tf)
#pragma unroll
        for (int r = 0; r < 4; ++r) mx = fmaxf(mx, st[tf][qi][r]);
      mx = fmaxf(mx, __shfl_xor(mx, 16));
      mx = fmaxf(mx, __shfl_xor(mx, 32));
      skip[qi] = __all(mx <= m_r[qi] + 8.0f);
      if (skip[qi]) {
        mnew[qi] = m_r[qi];                  // keep old max; P bounded by 2^8
        corr[qi] = 1.0f;
      } else {
        float mn = fmaxf(m_r[qi], mx);
        mnew[qi] = mn;
        corr[qi] = exp2fast(m_r[qi] - mn);
        m_r[qi] = mn;
      }
    }
    float lp[2] = {0.f, 0.f};
#pragma unroll
    for (int tf = 0; tf < 4; ++tf)
#pragma unroll
      for (int qi = 0; qi < 2; ++qi)
#pragma unroll
        for (int r = 0; r < 4; ++r) {
          float p = exp2fast(st[tf][qi][r] - mnew[qi]);
          st[tf][qi][r] = p;
          lp[qi] += p;
        }
#pragma unroll
    for (int qi = 0; qi < 2; ++qi) {
      lp[qi] += __shfl_xor(lp[qi], 16);
      lp[qi] += __shfl_xor(lp[qi], 32);
      l_r[qi] = skip[qi] ? (l_r[qi] + lp[qi]) : (l_r[qi] * corr[qi] + lp[qi]);
    }
    // order: previous iteration's ds_reads must stay before this iteration's ds_writes
    asm volatile("" ::: "memory");
    // P^T frag -> P_lds[q][t] via v_cvt_pk_bf16_f32 (packed b64 writes)
#pragma unroll
    for (int qi = 0; qi < 2; ++qi)
#pragma unroll
      for (int tf = 0; tf < 4; ++tf) {
        uint2 w;
        w.x = cvtpk(st[tf][qi][0], st[tf][qi][1]);
        w.y = cvtpk(st[tf][qi][2], st[tf][qi][3]);
        *(uint2*)&Pw[(qi * 16 + ln) * 72 + tf * 16 + lg * 4] = w;
      }
    asm volatile("s_waitcnt lgkmcnt(0)" ::: "memory");   // cross-lane P visibility
    // rescale O only when max actually grew (corr on lane&15=q; O rows are lg*4+r)
#pragma unroll
    for (int qi = 0; qi < 2; ++qi) {
      if (!skip[qi]) {
        float cr[4];
#pragma unroll
        for (int r = 0; r < 4; ++r) cr[r] = __shfl(corr[qi], lg * 4 + r, 16);
#pragma unroll
        for (int df = 0; df < 4; ++df)
#pragma unroll
          for (int r = 0; r < 4; ++r) o[qi][df][r] *= cr[r];
      }
    }
    // O += P @ V   (A = P[q][t] from LDS, B = V^T[d][t] from regs)
#pragma unroll
    for (int tk = 0; tk < 2; ++tk) {
      bf16x8 pa0 = *(const bf16x8*)&Pw[(0 * 16 + ln) * 72 + tk * 32 + lg * 8];
      bf16x8 pa1 = *(const bf16x8*)&Pw[(1 * 16 + ln) * 72 + tk * 32 + lg * 8];
#pragma unroll
      for (int df = 0; df < 4; ++df) {
        o[0][df] = mfma16(pa0, bv[tk][df], o[0][df]);
        o[1][df] = mfma16(pa1, bv[tk][df], o[1][df]);
      }
    }
  }
  // epilogue: O /= l, write [b*S][E] bf16
  const int h = bh % NH, b = bh / NH;
#pragma unroll
  for (int qi = 0; qi < 2; ++qi) {
    float li[4];
#pragma unroll
    for (int r = 0; r < 4; ++r) {
      float lv = __shfl(l_r[qi], lg * 4 + r, 16);
      li[r] = 1.0f / lv;
    }
#pragma unroll
    for (int df = 0; df < 4; ++df) {
      int ecol = h * HD + df * 16 + ln;
#pragma unroll
      for (int r = 0; r < 4; ++r) {
        int s = q0 + wave * 32 + qi * 16 + lg * 4 + r;
        Ob[((size_t)(b * SEQ + s)) * E_DIM + ecol] = f2b(o[qi][df][r] * li[r]);
      }
    }
  }
}

extern "C" void kernel_launch(void* const* d_in, const int* in_sizes, int n_in,
                              void* d_out, int out_size, void* d_ws, size_t ws_size,
                              hipStream_t stream) {
  const float* x    = (const float*)d_in[0];
  const float* Wqkv = (const float*)d_in[1];
  const float* bqkv = (const float*)d_in[2];
  const float* Wo   = (const float*)d_in[3];
  const float* bo   = (const float*)d_in[4];
  float* out = (float*)d_out;

  // ws needs only 29,884,416 B (~28.5 MiB). Q/K live in d_out (exactly out_size*4
  // = 25,165,824 B = 2 x 12,582,912 B) until k_gemm_out overwrites it last.
  // Ab aliases xb (xb fully consumed by k_gemm_qkv before k_attn writes Ab).
  char* ws = (char*)d_ws;
  u16* xb    = (u16*)(ws);                // [8192][768] bf16   12,582,912 B  (also Ab)
  u16* wqkvt = (u16*)(ws + 12582912);     // [2304][768]         3,538,944 B
  u16* wot   = (u16*)(ws + 16121856);     // [768][768]          1,179,648 B
  u16* Vtw   = (u16*)(ws + 17301504);     // [48][64][2048]     12,582,912 B
  u16* Ab    = xb;
  u16* Qw    = (u16*)d_out;               // [48][2048][64]     12,582,912 B
  u16* Kw    = (u16*)d_out + 6291456;     // [48][2048][64]     12,582,912 B

  k_cvt_x<<<dim3(6144), dim3(256), 0, stream>>>((const float4*)x, (uint2*)xb);
  k_wtrans<<<dim3(36, 12), dim3(256), 0, stream>>>(Wqkv, wqkvt, 768, 2304);
  k_wtrans<<<dim3(12, 12), dim3(256), 0, stream>>>(Wo, wot, 768, 768);
  k_gemm_qkv<<<dim3(64, 18), dim3(256), 0, stream>>>(xb, wqkvt, bqkv, Qw, Kw, Vtw);
  k_attn<<<dim3(768), dim3(256), 0, stream>>>(Qw, Kw, Vtw, Ab);
  k_gemm_out<<<dim3(64, 6), dim3(256), 0, stream>>>(Ab, wot, bo, out);
}

// Round 11
// 332.229 us; speedup vs baseline: 1.1592x; 1.1592x over previous
//
#include <hip/hip_runtime.h>
#include <cstdint>
#include <cstddef>

typedef unsigned short u16;
typedef unsigned int   u32;

#define E_DIM 768
#define NH    12
#define HD    64
#define SEQ   2048
#define NBATCH 4
#define NBH   48          // NBATCH*NH
#define MTOT  8192        // NBATCH*SEQ
#define NQKV  2304
// 0.125 * log2(e): QK^T scores land in log2 domain -> softmax uses raw v_exp_f32
#define QSCALE 0.18033688011112042f

typedef __bf16 bf16x8 __attribute__((ext_vector_type(8)));
typedef float  f32x4  __attribute__((ext_vector_type(4)));
typedef float  f32x16 __attribute__((ext_vector_type(16)));
typedef u32    u32x4  __attribute__((ext_vector_type(4)));

__device__ __forceinline__ u16 f2b(float f) {
  u32 u = __builtin_bit_cast(u32, f);
  u32 r = (u + 0x7fffu + ((u >> 16) & 1u)) >> 16;   // RNE, finite inputs only
  return (u16)r;
}
__device__ __forceinline__ u32 cvtpk(float a, float b) {   // dst = bf16(a) | bf16(b)<<16
  u32 r;
  asm("v_cvt_pk_bf16_f32 %0, %1, %2" : "=v"(r) : "v"(a), "v"(b));
  return r;
}
__device__ __forceinline__ float exp2fast(float x) {
  float r;
  asm("v_exp_f32 %0, %1" : "=v"(r) : "v"(x));
  return r;
}
__device__ __forceinline__ f32x4 mfma16(bf16x8 a, bf16x8 b, f32x4 c) {
  return __builtin_amdgcn_mfma_f32_16x16x32_bf16(a, b, c, 0, 0, 0);
}
__device__ __forceinline__ f32x16 mfma32(bf16x8 a, bf16x8 b, f32x16 c) {
  return __builtin_amdgcn_mfma_f32_32x32x16_bf16(a, b, c, 0, 0, 0);
}
__device__ __forceinline__ void gload_lds16(const void* g, void* l) {
  __builtin_amdgcn_global_load_lds((const __attribute__((address_space(1))) void*)g,
                                   (__attribute__((address_space(3))) void*)l, 16, 0, 0);
}

// ---------------- x fp32 -> bf16 ----------------
__global__ void k_cvt_x(const float4* __restrict__ x, uint2* __restrict__ xb) {
  int i = blockIdx.x * 256 + threadIdx.x;     // grid sized exactly: 6291456/4 elems
  float4 v = x[i];
  uint2 o;
  o.x = cvtpk(v.x, v.y);
  o.y = cvtpk(v.z, v.w);
  xb[i] = o;
}

// ------------- W [K][N] fp32 -> Wt [N][K] bf16 -------------
__global__ __launch_bounds__(256) void k_wtrans(const float* __restrict__ w, u16* __restrict__ wt,
                                                int K, int N) {
  __shared__ float t[64][65];
  int n0 = blockIdx.x * 64, k0 = blockIdx.y * 64;
  int tid = threadIdx.x;
#pragma unroll
  for (int it = 0; it < 16; ++it) {
    int idx = it * 256 + tid;
    int r = idx >> 6, c = idx & 63;          // r = k-local, c = n-local
    t[r][c] = w[(size_t)(k0 + r) * N + n0 + c];
  }
  __syncthreads();
#pragma unroll
  for (int it = 0; it < 16; ++it) {
    int idx = it * 256 + tid;
    int r = idx >> 6, c = idx & 63;          // r = n-local, c = k-local
    wt[(size_t)(n0 + r) * K + k0 + c] = f2b(t[c][r]);
  }
}

// ------------- GEMM mainloop (m97-style): A[M][768] bf16 x Bt[N][768] bf16 -------------
#define GEMM_MAIN(A_, Bt_)                                                              \
  __shared__ u16 As[128 * 32];                                                          \
  __shared__ u16 Bs[128 * 32];                                                          \
  const int tid = threadIdx.x;                                                          \
  const int m0 = blockIdx.x * 128, n0 = blockIdx.y * 128;                               \
  const int wave = tid >> 6, lane = tid & 63, ln = lane & 15, lg = lane >> 4;           \
  const int wr = wave >> 1, wc = wave & 1;                                              \
  f32x4 acc[4][4] = {};                                                                 \
  const int f0 = tid, f1 = tid + 256;                                                   \
  const size_t ga0 = (size_t)(m0 + (f0 >> 2)) * 768 + (f0 & 3) * 8;                     \
  const size_t ga1 = (size_t)(m0 + (f1 >> 2)) * 768 + (f1 & 3) * 8;                     \
  const size_t gb0 = (size_t)(n0 + (f0 >> 2)) * 768 + (f0 & 3) * 8;                     \
  const size_t gb1 = (size_t)(n0 + (f1 >> 2)) * 768 + (f1 & 3) * 8;                     \
  for (int kt = 0; kt < 24; ++kt) {                                                     \
    __syncthreads();                                                                    \
    gload_lds16(A_ + ga0 + kt * 32, &As[f0 * 8]);                                       \
    gload_lds16(A_ + ga1 + kt * 32, &As[f1 * 8]);                                       \
    gload_lds16(Bt_ + gb0 + kt * 32, &Bs[f0 * 8]);                                      \
    gload_lds16(Bt_ + gb1 + kt * 32, &Bs[f1 * 8]);                                      \
    __syncthreads();                                                                    \
    bf16x8 a[4], b[4];                                                                  \
    _Pragma("unroll") for (int i = 0; i < 4; ++i)                                       \
        a[i] = *(const bf16x8*)&As[(wr * 64 + i * 16 + ln) * 32 + lg * 8];              \
    _Pragma("unroll") for (int j = 0; j < 4; ++j)                                       \
        b[j] = *(const bf16x8*)&Bs[(wc * 64 + j * 16 + ln) * 32 + lg * 8];              \
    _Pragma("unroll") for (int i = 0; i < 4; ++i)                                       \
        _Pragma("unroll") for (int j = 0; j < 4; ++j)                                   \
            acc[i][j] = mfma16(a[i], b[j], acc[i][j]);                                  \
  }

// qkv = x @ Wqkv + b; scatter into Q(*QSCALE)/K [bh][s][d] and V^T [bh][d][s], all bf16
__global__ __launch_bounds__(256) void k_gemm_qkv(const u16* __restrict__ A, const u16* __restrict__ Bt,
                                                  const float* __restrict__ bias,
                                                  u16* __restrict__ Qw, u16* __restrict__ Kw,
                                                  u16* __restrict__ Vt) {
  GEMM_MAIN(A, Bt)
#pragma unroll
  for (int j = 0; j < 4; ++j) {
    int n = n0 + wc * 64 + j * 16 + ln;      // uniform route per frag (16-block never straddles 64-aligned splits)
    float bn = bias[n];
    if (n >= 1536) {                         // V: write transposed [bh][d][s], 4 consecutive s packed
      int h = (n - 1536) >> 6, d = (n - 1536) & 63;
#pragma unroll
      for (int i = 0; i < 4; ++i) {
        int mb = m0 + wr * 64 + i * 16 + lg * 4;   // 4-aligned; never crosses batch (2048|4)
        int bb = mb >> 11, s = mb & 2047;
        uint2 w;
        w.x = cvtpk(acc[i][j][0] + bn, acc[i][j][1] + bn);
        w.y = cvtpk(acc[i][j][2] + bn, acc[i][j][3] + bn);
        *(uint2*)&Vt[((size_t)(bb * NH + h) * HD + d) * SEQ + s] = w;
      }
    } else {
      u16* dst; int nn; float scale;
      if (n < 768) { dst = Qw; nn = n;       scale = QSCALE; }
      else         { dst = Kw; nn = n - 768; scale = 1.0f;  }
      int h = nn >> 6, d = nn & 63;
#pragma unroll
      for (int i = 0; i < 4; ++i) {
        int mb = m0 + wr * 64 + i * 16 + lg * 4;
#pragma unroll
        for (int r = 0; r < 4; ++r) {
          int m = mb + r;
          int bb = m >> 11, s = m & 2047;
          float v = (acc[i][j][r] + bn) * scale;
          dst[((size_t)(bb * NH + h) * SEQ + s) * HD + d] = f2b(v);
        }
      }
    }
  }
}

// out = attn_bf @ Wo + bo  (fp32 out)
__global__ __launch_bounds__(256) void k_gemm_out(const u16* __restrict__ A, const u16* __restrict__ Bt,
                                                  const float* __restrict__ bias, float* __restrict__ C) {
  GEMM_MAIN(A, Bt)
#pragma unroll
  for (int j = 0; j < 4; ++j) {
    int n = n0 + wc * 64 + j * 16 + ln;
    float bn = bias[n];
#pragma unroll
    for (int i = 0; i < 4; ++i) {
      int mb = m0 + wr * 64 + i * 16 + lg * 4;
#pragma unroll
      for (int r = 0; r < 4; ++r) {
        C[(size_t)(mb + r) * 768 + n] = acc[i][j][r] + bn;
      }
    }
  }
}

// ------------- flash attention, 32x32 swapped-operand, in-register softmax -------------
// Q[bh][s][d] (pre-scaled, log2 domain), K[bh][s][d], Vt[bh][d][s] -> Ob[b*S][E] bf16.
// S^T[t][q] = mfma32(K_frag, Q_frag): q = lane&31 (lane-local stats);
// O^T[d][q] = mfma32(V^T_frag, P^T_frag): same q -> rescale/divide lane-local.
// P^T B-frags via v_cvt_pk_bf16_f32 + v_permlane32_swap_b32 (vdst.hi <-> vsrc.lo):
// vdst = low-t pack, vsrc = high-t pack  [fixed from r9: roles were inverted].
// No LDS. KVBLK=32. Defer-max THR=8 (log2 domain).
__global__ __launch_bounds__(256, 3) void k_attn(const u16* __restrict__ Qw, const u16* __restrict__ Kw,
                                                 const u16* __restrict__ Vt, u16* __restrict__ Ob) {
  // XCD-bijective swizzle: 768 blocks = 8 XCDs x 96; one head's 16 q-tiles + 6 heads per XCD
  const int wg = (blockIdx.x & 7) * 96 + (blockIdx.x >> 3);
  const int bh = wg >> 4;
  const int q0 = (wg & 15) * 128;
  const int wv = threadIdx.x >> 6, lane = threadIdx.x & 63;
  const int ql = lane & 31, hi = lane >> 5;
  const u16* Qb = Qw + ((size_t)bh * SEQ + q0 + wv * 32) * HD;
  const u16* Kb = Kw + (size_t)bh * SEQ * HD;
  const u16* Vb = Vt + (size_t)bh * HD * SEQ;

  // Q B-frags: B[k=dk][col=q]; lane holds q=ql, dk = ks*16 + hi*8 + j
  bf16x8 qf[4];
#pragma unroll
  for (int ks = 0; ks < 4; ++ks)
    qf[ks] = *(const bf16x8*)&Qb[ql * HD + ks * 16 + hi * 8];

  f32x16 ot0 = {}, ot1 = {};                 // O^T d-halves; col=q lane-local
  float m_r = -1e30f, l_r = 0.f;

  for (int t0 = 0; t0 < SEQ; t0 += 32) {
    // K A-frags: A[row=t][k=dk]; row = ql, dk = ks*16 + hi*8 + j
    bf16x8 kf[4];
#pragma unroll
    for (int ks = 0; ks < 4; ++ks)
      kf[ks] = *(const bf16x8*)&Kb[(size_t)(t0 + ql) * HD + ks * 16 + hi * 8];
    // V A-frags: A[row=d][k=t]; row = dh*32+ql, t = t0 + ks2*16 + hi*8 + j
    bf16x8 vf[2][2];
#pragma unroll
    for (int dh = 0; dh < 2; ++dh)
#pragma unroll
      for (int ks2 = 0; ks2 < 2; ++ks2)
        vf[dh][ks2] = *(const bf16x8*)&Vb[(size_t)(dh * 32 + ql) * SEQ + t0 + ks2 * 16 + hi * 8];

    // S^T = K*Q : D[t][q], t_local = (r&3)+8*(r>>2)+4*hi, q = ql
    f32x16 s = {};
#pragma unroll
    for (int ks = 0; ks < 4; ++ks) s = mfma32(kf[ks], qf[ks], s);

    // per-lane max over own 16 t + partner's 16 (shfl_xor 32)
    float tm[8];
#pragma unroll
    for (int r = 0; r < 8; ++r) tm[r] = fmaxf(s[r], s[r + 8]);
#pragma unroll
    for (int st = 4; st > 0; st >>= 1)
#pragma unroll
      for (int r = 0; r < 4; ++r) if (r < st) tm[r] = fmaxf(tm[r], tm[r + st]);
    float mx = fmaxf(tm[0], __shfl_xor(tm[0], 32));

    bool skip = __all(mx <= m_r + 8.0f);
    float mnew, corr = 1.0f;
    if (skip) {
      mnew = m_r;                            // keep old max; P bounded by 2^8
    } else {
      mnew = fmaxf(m_r, mx);
      corr = exp2fast(m_r - mnew);
      m_r = mnew;
    }
    // P = 2^(s - mnew), row-sum
#pragma unroll
    for (int r = 0; r < 16; ++r) s[r] = exp2fast(s[r] - mnew);
    float ts[8];
#pragma unroll
    for (int r = 0; r < 8; ++r) ts[r] = s[r] + s[r + 8];
#pragma unroll
    for (int st = 4; st > 0; st >>= 1)
#pragma unroll
      for (int r = 0; r < 4; ++r) if (r < st) ts[r] += ts[r + st];
    float la = ts[0] + __shfl_xor(ts[0], 32);
    l_r = skip ? (l_r + la) : (l_r * corr + la);
    if (!skip) {
#pragma unroll
      for (int r = 0; r < 16; ++r) { ot0[r] *= corr; ot1[r] *= corr; }
    }

    // P^T B-frags: B[k=t][col=q]. Per-lane need: k = ks2*16 + hi*8 + j.
    // swap(vdst=pk(s0,s1), vsrc=pk(s4,s5)) [vdst.hi<->vsrc.lo]:
    //   vdst: hi0=(t0,t1) hi1=(t8,t9) -> w0 ; vsrc: hi0=(t4,t5) hi1=(t12,t13) -> w2
    u32 w0, w1, w2, w3;
    w0 = cvtpk(s[0], s[1]);  w2 = cvtpk(s[4], s[5]);
    asm("v_permlane32_swap_b32 %0, %1" : "+v"(w0), "+v"(w2));
    w1 = cvtpk(s[2], s[3]);  w3 = cvtpk(s[6], s[7]);
    asm("v_permlane32_swap_b32 %0, %1" : "+v"(w1), "+v"(w3));
    bf16x8 pf0 = __builtin_bit_cast(bf16x8, (u32x4){w0, w1, w2, w3});
    w0 = cvtpk(s[8], s[9]);   w2 = cvtpk(s[12], s[13]);
    asm("v_permlane32_swap_b32 %0, %1" : "+v"(w0), "+v"(w2));
    w1 = cvtpk(s[10], s[11]); w3 = cvtpk(s[14], s[15]);
    asm("v_permlane32_swap_b32 %0, %1" : "+v"(w1), "+v"(w3));
    bf16x8 pf1 = __builtin_bit_cast(bf16x8, (u32x4){w0, w1, w2, w3});

    // O^T += V^T * P^T
    ot0 = mfma32(vf[0][0], pf0, ot0);
    ot1 = mfma32(vf[1][0], pf0, ot1);
    ot0 = mfma32(vf[0][1], pf1, ot0);
    ot1 = mfma32(vf[1][1], pf1, ot1);
  }

  // epilogue: O^T[d][q] /= l[q] (lane-local), write [b*S][E] bf16
  const int h = bh % NH, b = bh / NH;
  const float inv = 1.0f / l_r;
  const int sg = q0 + wv * 32 + ql;
  u16* row = Ob + (size_t)(b * SEQ + sg) * E_DIM + h * HD;
#pragma unroll
  for (int rp = 0; rp < 8; ++rp) {
    int r = rp * 2;
    int d = (r & 3) + 8 * (r >> 2) + 4 * hi;
    *(u32*)&row[d]      = cvtpk(ot0[r] * inv, ot0[r + 1] * inv);
    *(u32*)&row[d + 32] = cvtpk(ot1[r] * inv, ot1[r + 1] * inv);
  }
}

extern "C" void kernel_launch(void* const* d_in, const int* in_sizes, int n_in,
                              void* d_out, int out_size, void* d_ws, size_t ws_size,
                              hipStream_t stream) {
  const float* x    = (const float*)d_in[0];
  const float* Wqkv = (const float*)d_in[1];
  const float* bqkv = (const float*)d_in[2];
  const float* Wo   = (const float*)d_in[3];
  const float* bo   = (const float*)d_in[4];
  float* out = (float*)d_out;

  // ws needs only 29,884,416 B (~28.5 MiB). Q/K live in d_out (exactly out_size*4
  // = 25,165,824 B = 2 x 12,582,912 B) until k_gemm_out overwrites it last.
  // Ab aliases xb (xb fully consumed by k_gemm_qkv before k_attn writes Ab).
  char* ws = (char*)d_ws;
  u16* xb    = (u16*)(ws);                // [8192][768] bf16   12,582,912 B  (also Ab)
  u16* wqkvt = (u16*)(ws + 12582912);     // [2304][768]         3,538,944 B
  u16* wot   = (u16*)(ws + 16121856);     // [768][768]          1,179,648 B
  u16* Vtw   = (u16*)(ws + 17301504);     // [48][64][2048]     12,582,912 B
  u16* Ab    = xb;
  u16* Qw    = (u16*)d_out;               // [48][2048][64]     12,582,912 B
  u16* Kw    = (u16*)d_out + 6291456;     // [48][2048][64]     12,582,912 B

  k_cvt_x<<<dim3(6144), dim3(256), 0, stream>>>((const float4*)x, (uint2*)xb);
  k_wtrans<<<dim3(36, 12), dim3(256), 0, stream>>>(Wqkv, wqkvt, 768, 2304);
  k_wtrans<<<dim3(12, 12), dim3(256), 0, stream>>>(Wo, wot, 768, 768);
  k_gemm_qkv<<<dim3(64, 18), dim3(256), 0, stream>>>(xb, wqkvt, bqkv, Qw, Kw, Vtw);
  k_attn<<<dim3(768), dim3(256), 0, stream>>>(Qw, Kw, Vtw, Ab);
  k_gemm_out<<<dim3(64, 6), dim3(256), 0, stream>>>(Ab, wot, bo, out);
}

// Round 12
// 225.991 us; speedup vs baseline: 1.7042x; 1.4701x over previous
//
#include <hip/hip_runtime.h>
#include <cstdint>
#include <cstddef>

typedef unsigned short u16;
typedef unsigned int   u32;

#define E_DIM 768
#define NH    12
#define HD    64
#define SEQ   2048
#define NBATCH 4
#define NBH   48          // NBATCH*NH
#define MTOT  8192        // NBATCH*SEQ
#define NQKV  2304
// 0.125 * log2(e): QK^T scores land in log2 domain -> softmax uses raw v_exp_f32
#define QSCALE 0.18033688011112042f
// per-head element count of the tiled K / V^T buffers: 64 tiles x 2048 elems
#define HSTRIDE 131072

typedef __bf16 bf16x8 __attribute__((ext_vector_type(8)));
typedef float  f32x4  __attribute__((ext_vector_type(4)));
typedef float  f32x16 __attribute__((ext_vector_type(16)));
typedef u32    u32x4  __attribute__((ext_vector_type(4)));

__device__ __forceinline__ u16 f2b(float f) {
  u32 u = __builtin_bit_cast(u32, f);
  u32 r = (u + 0x7fffu + ((u >> 16) & 1u)) >> 16;   // RNE, finite inputs only
  return (u16)r;
}
__device__ __forceinline__ u32 cvtpk(float a, float b) {   // dst = bf16(a) | bf16(b)<<16
  u32 r;
  asm("v_cvt_pk_bf16_f32 %0, %1, %2" : "=v"(r) : "v"(a), "v"(b));
  return r;
}
__device__ __forceinline__ float exp2fast(float x) {
  float r;
  asm("v_exp_f32 %0, %1" : "=v"(r) : "v"(x));
  return r;
}
__device__ __forceinline__ f32x4 mfma16(bf16x8 a, bf16x8 b, f32x4 c) {
  return __builtin_amdgcn_mfma_f32_16x16x32_bf16(a, b, c, 0, 0, 0);
}
__device__ __forceinline__ f32x16 mfma32(bf16x8 a, bf16x8 b, f32x16 c) {
  return __builtin_amdgcn_mfma_f32_32x32x16_bf16(a, b, c, 0, 0, 0);
}
__device__ __forceinline__ void gload_lds16(const void* g, void* l) {
  __builtin_amdgcn_global_load_lds((const __attribute__((address_space(1))) void*)g,
                                   (__attribute__((address_space(3))) void*)l, 16, 0, 0);
}

// ---------------- x fp32 -> bf16 ----------------
__global__ void k_cvt_x(const float4* __restrict__ x, uint2* __restrict__ xb) {
  int i = blockIdx.x * 256 + threadIdx.x;     // grid sized exactly: 6291456/4 elems
  float4 v = x[i];
  uint2 o;
  o.x = cvtpk(v.x, v.y);
  o.y = cvtpk(v.z, v.w);
  xb[i] = o;
}

// ------------- W [K][N] fp32 -> Wt [N][K] bf16 -------------
__global__ __launch_bounds__(256) void k_wtrans(const float* __restrict__ w, u16* __restrict__ wt,
                                                int K, int N) {
  __shared__ float t[64][65];
  int n0 = blockIdx.x * 64, k0 = blockIdx.y * 64;
  int tid = threadIdx.x;
#pragma unroll
  for (int it = 0; it < 16; ++it) {
    int idx = it * 256 + tid;
    int r = idx >> 6, c = idx & 63;          // r = k-local, c = n-local
    t[r][c] = w[(size_t)(k0 + r) * N + n0 + c];
  }
  __syncthreads();
#pragma unroll
  for (int it = 0; it < 16; ++it) {
    int idx = it * 256 + tid;
    int r = idx >> 6, c = idx & 63;          // r = n-local, c = k-local
    wt[(size_t)(n0 + r) * K + k0 + c] = f2b(t[c][r]);
  }
}

// ------------- GEMM mainloop (m97-style): A[M][768] bf16 x Bt[N][768] bf16 -------------
#define GEMM_MAIN(A_, Bt_)                                                              \
  __shared__ u16 As[128 * 32];                                                          \
  __shared__ u16 Bs[128 * 32];                                                          \
  const int tid = threadIdx.x;                                                          \
  const int m0 = blockIdx.x * 128, n0 = blockIdx.y * 128;                               \
  const int wave = tid >> 6, lane = tid & 63, ln = lane & 15, lg = lane >> 4;           \
  const int wr = wave >> 1, wc = wave & 1;                                              \
  f32x4 acc[4][4] = {};                                                                 \
  const int f0 = tid, f1 = tid + 256;                                                   \
  const size_t ga0 = (size_t)(m0 + (f0 >> 2)) * 768 + (f0 & 3) * 8;                     \
  const size_t ga1 = (size_t)(m0 + (f1 >> 2)) * 768 + (f1 & 3) * 8;                     \
  const size_t gb0 = (size_t)(n0 + (f0 >> 2)) * 768 + (f0 & 3) * 8;                     \
  const size_t gb1 = (size_t)(n0 + (f1 >> 2)) * 768 + (f1 & 3) * 8;                     \
  for (int kt = 0; kt < 24; ++kt) {                                                     \
    __syncthreads();                                                                    \
    gload_lds16(A_ + ga0 + kt * 32, &As[f0 * 8]);                                       \
    gload_lds16(A_ + ga1 + kt * 32, &As[f1 * 8]);                                       \
    gload_lds16(Bt_ + gb0 + kt * 32, &Bs[f0 * 8]);                                      \
    gload_lds16(Bt_ + gb1 + kt * 32, &Bs[f1 * 8]);                                      \
    __syncthreads();                                                                    \
    bf16x8 a[4], b[4];                                                                  \
    _Pragma("unroll") for (int i = 0; i < 4; ++i)                                       \
        a[i] = *(const bf16x8*)&As[(wr * 64 + i * 16 + ln) * 32 + lg * 8];              \
    _Pragma("unroll") for (int j = 0; j < 4; ++j)                                       \
        b[j] = *(const bf16x8*)&Bs[(wc * 64 + j * 16 + ln) * 32 + lg * 8];              \
    _Pragma("unroll") for (int i = 0; i < 4; ++i)                                       \
        _Pragma("unroll") for (int j = 0; j < 4; ++j)                                   \
            acc[i][j] = mfma16(a[i], b[j], acc[i][j]);                                  \
  }

// qkv = x @ Wqkv + b; Q(*QSCALE) [bh][s][d]; K tiled [bh][t32][ks][hi][t][8dk];
// V^T tiled [bh][t32][ks2*2+hi][d][8t]. All bf16.
__global__ __launch_bounds__(256) void k_gemm_qkv(const u16* __restrict__ A, const u16* __restrict__ Bt,
                                                  const float* __restrict__ bias,
                                                  u16* __restrict__ Qw, u16* __restrict__ Kw,
                                                  u16* __restrict__ Vt) {
  GEMM_MAIN(A, Bt)
#pragma unroll
  for (int j = 0; j < 4; ++j) {
    int n = n0 + wc * 64 + j * 16 + ln;      // uniform route per frag (16-block never straddles 64-aligned splits)
    float bn = bias[n];
    if (n >= 1536) {                         // V^T tiled: elem (s,d) -> tile=s>>5, (bit4(s)*2+bit3(s))*512 + d*8 + (s&7)
      int h = (n - 1536) >> 6, d = (n - 1536) & 63;
#pragma unroll
      for (int i = 0; i < 4; ++i) {
        int mb = m0 + wr * 64 + i * 16 + lg * 4;   // 4-aligned; 4 consecutive s stay in one j-run
        int bb = mb >> 11, s0 = mb & 2047;
        size_t off = (size_t)(bb * NH + h) * HSTRIDE + (size_t)(s0 >> 5) * 2048
                   + (((s0 >> 4) & 1) * 2 + ((s0 >> 3) & 1)) * 512 + d * 8 + (s0 & 7);
        uint2 w;
        w.x = cvtpk(acc[i][j][0] + bn, acc[i][j][1] + bn);
        w.y = cvtpk(acc[i][j][2] + bn, acc[i][j][3] + bn);
        *(uint2*)&Vt[off] = w;
      }
    } else if (n >= 768) {                   // K tiled: elem (s,d) -> tile=s>>5, ((d>>4)*2+bit3(d))*256 + (s&31)*8 + (d&7)
      int nn = n - 768, h = nn >> 6, d = nn & 63;
      int kslot = ((d >> 4) * 2 + ((d >> 3) & 1)) * 256 + (d & 7);
#pragma unroll
      for (int i = 0; i < 4; ++i) {
        int mb = m0 + wr * 64 + i * 16 + lg * 4;
        int bb = mb >> 11, s0 = mb & 2047;
        size_t base = (size_t)(bb * NH + h) * HSTRIDE + (size_t)(s0 >> 5) * 2048
                    + kslot + (s0 & 31) * 8;
#pragma unroll
        for (int r = 0; r < 4; ++r)
          Kw[base + r * 8] = f2b(acc[i][j][r] + bn);
      }
    } else {                                 // Q row-major [bh][s][d], pre-scaled
      int h = n >> 6, d = n & 63;
#pragma unroll
      for (int i = 0; i < 4; ++i) {
        int mb = m0 + wr * 64 + i * 16 + lg * 4;
#pragma unroll
        for (int r = 0; r < 4; ++r) {
          int m = mb + r;
          int bb = m >> 11, s = m & 2047;
          Qw[((size_t)(bb * NH + h) * SEQ + s) * HD + d] = f2b((acc[i][j][r] + bn) * QSCALE);
        }
      }
    }
  }
}

// out = attn_bf @ Wo + bo  (fp32 out)
__global__ __launch_bounds__(256) void k_gemm_out(const u16* __restrict__ A, const u16* __restrict__ Bt,
                                                  const float* __restrict__ bias, float* __restrict__ C) {
  GEMM_MAIN(A, Bt)
#pragma unroll
  for (int j = 0; j < 4; ++j) {
    int n = n0 + wc * 64 + j * 16 + ln;
    float bn = bias[n];
#pragma unroll
    for (int i = 0; i < 4; ++i) {
      int mb = m0 + wr * 64 + i * 16 + lg * 4;
#pragma unroll
      for (int r = 0; r < 4; ++r) {
        C[(size_t)(mb + r) * 768 + n] = acc[i][j][r] + bn;
      }
    }
  }
}

// ------------- flash attention, 32x32 swapped-operand, in-register softmax -------------
// Q[bh][s][d] (pre-scaled, log2 domain); K/V^T in fragment-ready tiled layouts.
// Per t-tile (32): one coalesced LDS stage per BLOCK (global_load_lds, linear src+dst,
// double-buffered, stage-next -> compute-current -> vmcnt(0)+barrier). Fragments via
// conflict-free contiguous-16B ds_read_b128. Softmax fully in-register (q = lane&31).
__global__ __launch_bounds__(256, 3) void k_attn(const u16* __restrict__ Qw, const u16* __restrict__ Kw,
                                                 const u16* __restrict__ Vt, u16* __restrict__ Ob) {
  __shared__ __align__(16) u16 Kbuf[2][2048];   // [ks][hi][t][8dk] per tile
  __shared__ __align__(16) u16 Vbuf[2][2048];   // [ks2*2+hi][d][8t] per tile
  // XCD-bijective swizzle: 768 blocks = 8 XCDs x 96; one head's 16 q-tiles + 6 heads per XCD
  const int wg = (blockIdx.x & 7) * 96 + (blockIdx.x >> 3);
  const int bh = wg >> 4;
  const int q0 = (wg & 15) * 128;
  const int wv = threadIdx.x >> 6, lane = threadIdx.x & 63;
  const int ql = lane & 31, hi = lane >> 5;
  const u16* Qb  = Qw + ((size_t)bh * SEQ + q0 + wv * 32) * HD;
  const u16* KTb = Kw + (size_t)bh * HSTRIDE;
  const u16* VTb = Vt + (size_t)bh * HSTRIDE;
  const int soff = wv * 512 + lane * 8;         // this wave's staging slice (1 KB of each tile)

  // Q B-frags: B[k=dk][col=q]; lane holds q=ql, dk = ks*16 + hi*8 + j  (once per kernel)
  bf16x8 qf[4];
#pragma unroll
  for (int ks = 0; ks < 4; ++ks)
    qf[ks] = *(const bf16x8*)&Qb[ql * HD + ks * 16 + hi * 8];

  f32x16 ot0 = {}, ot1 = {};                 // O^T d-halves; col=q lane-local
  float m_r = -1e30f, l_r = 0.f;

  // prologue: stage tile 0 into buf 0
  gload_lds16(KTb + soff, &Kbuf[0][soff]);
  gload_lds16(VTb + soff, &Vbuf[0][soff]);
  asm volatile("s_waitcnt vmcnt(0)" ::: "memory");
  __syncthreads();

  int cur = 0;
  for (int tt = 0; tt < 64; ++tt) {
    // issue next tile's stage first (latency hides under this tile's compute)
    if (tt + 1 < 64) {
      gload_lds16(KTb + (size_t)(tt + 1) * 2048 + soff, &Kbuf[cur ^ 1][soff]);
      gload_lds16(VTb + (size_t)(tt + 1) * 2048 + soff, &Vbuf[cur ^ 1][soff]);
    }
    // fragments from LDS (contiguous 16B per lane; conflict-free)
    bf16x8 kf[4], vf[2][2];
#pragma unroll
    for (int ks = 0; ks < 4; ++ks)
      kf[ks] = *(const bf16x8*)&Kbuf[cur][(ks * 2 + hi) * 256 + ql * 8];
#pragma unroll
    for (int dh = 0; dh < 2; ++dh)
#pragma unroll
      for (int ks2 = 0; ks2 < 2; ++ks2)
        vf[dh][ks2] = *(const bf16x8*)&Vbuf[cur][(ks2 * 2 + hi) * 512 + (dh * 32 + ql) * 8];

    // S^T = K*Q : D[t][q], t_local = (r&3)+8*(r>>2)+4*hi, q = ql
    f32x16 s = {};
#pragma unroll
    for (int ks = 0; ks < 4; ++ks) s = mfma32(kf[ks], qf[ks], s);

    // per-lane max over own 16 t + partner's 16 (shfl_xor 32)
    float tm[8];
#pragma unroll
    for (int r = 0; r < 8; ++r) tm[r] = fmaxf(s[r], s[r + 8]);
#pragma unroll
    for (int st = 4; st > 0; st >>= 1)
#pragma unroll
      for (int r = 0; r < 4; ++r) if (r < st) tm[r] = fmaxf(tm[r], tm[r + st]);
    float mx = fmaxf(tm[0], __shfl_xor(tm[0], 32));

    bool skip = __all(mx <= m_r + 8.0f);
    float mnew, corr = 1.0f;
    if (skip) {
      mnew = m_r;                            // keep old max; P bounded by 2^8
    } else {
      mnew = fmaxf(m_r, mx);
      corr = exp2fast(m_r - mnew);
      m_r = mnew;
    }
    // P = 2^(s - mnew), row-sum
#pragma unroll
    for (int r = 0; r < 16; ++r) s[r] = exp2fast(s[r] - mnew);
    float ts[8];
#pragma unroll
    for (int r = 0; r < 8; ++r) ts[r] = s[r] + s[r + 8];
#pragma unroll
    for (int st = 4; st > 0; st >>= 1)
#pragma unroll
      for (int r = 0; r < 4; ++r) if (r < st) ts[r] += ts[r + st];
    float la = ts[0] + __shfl_xor(ts[0], 32);
    l_r = skip ? (l_r + la) : (l_r * corr + la);
    if (!skip) {
#pragma unroll
      for (int r = 0; r < 16; ++r) { ot0[r] *= corr; ot1[r] *= corr; }
    }

    // P^T B-frags: B[k=t][col=q]. swap(vdst=low-t pack, vsrc=high-t pack): vdst.hi<->vsrc.lo
    u32 w0, w1, w2, w3;
    w0 = cvtpk(s[0], s[1]);  w2 = cvtpk(s[4], s[5]);
    asm("v_permlane32_swap_b32 %0, %1" : "+v"(w0), "+v"(w2));
    w1 = cvtpk(s[2], s[3]);  w3 = cvtpk(s[6], s[7]);
    asm("v_permlane32_swap_b32 %0, %1" : "+v"(w1), "+v"(w3));
    bf16x8 pf0 = __builtin_bit_cast(bf16x8, (u32x4){w0, w1, w2, w3});
    w0 = cvtpk(s[8], s[9]);   w2 = cvtpk(s[12], s[13]);
    asm("v_permlane32_swap_b32 %0, %1" : "+v"(w0), "+v"(w2));
    w1 = cvtpk(s[10], s[11]); w3 = cvtpk(s[14], s[15]);
    asm("v_permlane32_swap_b32 %0, %1" : "+v"(w1), "+v"(w3));
    bf16x8 pf1 = __builtin_bit_cast(bf16x8, (u32x4){w0, w1, w2, w3});

    // O^T += V^T * P^T
    ot0 = mfma32(vf[0][0], pf0, ot0);
    ot1 = mfma32(vf[1][0], pf0, ot1);
    ot0 = mfma32(vf[0][1], pf1, ot0);
    ot1 = mfma32(vf[1][1], pf1, ot1);

    // drain this iteration's stage issues; all waves sync before buffers flip
    asm volatile("s_waitcnt vmcnt(0)" ::: "memory");
    __syncthreads();
    cur ^= 1;
  }

  // epilogue: O^T[d][q] /= l[q] (lane-local), write [b*S][E] bf16
  const int h = bh % NH, b = bh / NH;
  const float inv = 1.0f / l_r;
  const int sg = q0 + wv * 32 + ql;
  u16* row = Ob + (size_t)(b * SEQ + sg) * E_DIM + h * HD;
#pragma unroll
  for (int rp = 0; rp < 8; ++rp) {
    int r = rp * 2;
    int d = (r & 3) + 8 * (r >> 2) + 4 * hi;
    *(u32*)&row[d]      = cvtpk(ot0[r] * inv, ot0[r + 1] * inv);
    *(u32*)&row[d + 32] = cvtpk(ot1[r] * inv, ot1[r + 1] * inv);
  }
}

extern "C" void kernel_launch(void* const* d_in, const int* in_sizes, int n_in,
                              void* d_out, int out_size, void* d_ws, size_t ws_size,
                              hipStream_t stream) {
  const float* x    = (const float*)d_in[0];
  const float* Wqkv = (const float*)d_in[1];
  const float* bqkv = (const float*)d_in[2];
  const float* Wo   = (const float*)d_in[3];
  const float* bo   = (const float*)d_in[4];
  float* out = (float*)d_out;

  // ws needs only 29,884,416 B (~28.5 MiB). Q/K live in d_out (exactly out_size*4
  // = 25,165,824 B = 2 x 12,582,912 B) until k_gemm_out overwrites it last.
  // Ab aliases xb (xb fully consumed by k_gemm_qkv before k_attn writes Ab).
  char* ws = (char*)d_ws;
  u16* xb    = (u16*)(ws);                // [8192][768] bf16   12,582,912 B  (also Ab)
  u16* wqkvt = (u16*)(ws + 12582912);     // [2304][768]         3,538,944 B
  u16* wot   = (u16*)(ws + 16121856);     // [768][768]          1,179,648 B
  u16* Vtw   = (u16*)(ws + 17301504);     // [48][64][2048] tiled 12,582,912 B
  u16* Ab    = xb;
  u16* Qw    = (u16*)d_out;               // [48][2048][64]     12,582,912 B
  u16* Kw    = (u16*)d_out + 6291456;     // [48] tiled         12,582,912 B

  k_cvt_x<<<dim3(6144), dim3(256), 0, stream>>>((const float4*)x, (uint2*)xb);
  k_wtrans<<<dim3(36, 12), dim3(256), 0, stream>>>(Wqkv, wqkvt, 768, 2304);
  k_wtrans<<<dim3(12, 12), dim3(256), 0, stream>>>(Wo, wot, 768, 768);
  k_gemm_qkv<<<dim3(64, 18), dim3(256), 0, stream>>>(xb, wqkvt, bqkv, Qw, Kw, Vtw);
  k_attn<<<dim3(768), dim3(256), 0, stream>>>(Qw, Kw, Vtw, Ab);
  k_gemm_out<<<dim3(64, 6), dim3(256), 0, stream>>>(Ab, wot, bo, out);
}